// Round 1
// baseline (64.255 us; speedup 1.0000x reference)
//
#include <hip/hip_runtime.h>

#define NTOK 16384
#define HID  4096
#define NEXP 64
#define BM   64
#define BK   64
#define NSTEPS (HID / BK)   // 64

typedef _Float16 f16;
typedef f16  f16x4 __attribute__((ext_vector_type(4)));
typedef f16  f16x8 __attribute__((ext_vector_type(8)));
typedef float f32x4 __attribute__((ext_vector_type(4)));

// LDS planes: [row][64 k] fp16, row stride 128 B = 8 units of 16 B.
// XOR-swizzle unit index with (row&7) so 16-lane fragment reads (rows = lane&15,
// fixed unit) spread across all 8 bank-quads (2-way = free).
__device__ __forceinline__ int swz_base(int row, int unit) {
    return row * 64 + ((unit ^ (row & 7)) << 3);
}

__global__ __launch_bounds__(512)
void topk_gate_kernel(const float* __restrict__ x,
                      const float* __restrict__ w,
                      float* __restrict__ out) {
    __shared__ __align__(16) f16 Ah[BM * BK];
    __shared__ __align__(16) f16 Al[BM * BK];
    __shared__ __align__(16) f16 Bh[NEXP * BK];
    __shared__ __align__(16) f16 Bl[NEXP * BK];
    __shared__ float red[2][BM][4];

    const int t    = threadIdx.x;
    const int blk  = blockIdx.x;
    const int lane = t & 63;
    const int wid  = t >> 6;       // 0..7
    const int wm   = wid & 3;      // token quarter of the 64-token tile
    const int wn   = wid >> 2;     // expert half (0: experts 0-31, 1: 32-63)

    // ---- staging role: threads 0-255 stage x (A), 256-511 stage w (B) ----
    const bool isB   = (t >= 256);
    const int  tt    = t & 255;
    const int  srow  = tt >> 2;            // 0..63
    const int  sq    = (tt & 3) * 4;       // quad base within row: 0,4,8,12
    // scale w by 64 (exact, power of 2) so w_lo avoids fp16 subnormal loss
    const float scale = isB ? 64.0f : 1.0f;
    const float* src = isB ? (w + (size_t)srow * HID + sq * 4)
                           : (x + ((size_t)blk * BM + srow) * HID + sq * 4);
    f16* dstH = isB ? Bh : Ah;
    f16* dstL = isB ? Bl : Al;

    f32x4 acc0 = {0.f, 0.f, 0.f, 0.f};   // experts wn*32 + (lane&15)
    f32x4 acc1 = {0.f, 0.f, 0.f, 0.f};   // experts wn*32 + 16 + (lane&15)

    const int col = lane & 15;
    const int grp = lane >> 4;

    // prologue: load step 0 into registers
    float4 cur[4];
    #pragma unroll
    for (int i = 0; i < 4; ++i)
        cur[i] = *(const float4*)(src + 0 * BK + i * 4);

    for (int s = 0; s < NSTEPS; ++s) {
        // issue next step's global loads early (overlap with convert+compute)
        const int sn = (s + 1 < NSTEPS) ? (s + 1) : s;
        float4 nxt[4];
        #pragma unroll
        for (int i = 0; i < 4; ++i)
            nxt[i] = *(const float4*)(src + (size_t)sn * BK + i * 4);

        __syncthreads();   // previous step's LDS reads complete

        // convert cur -> hi/lo fp16 planes in LDS
        #pragma unroll
        for (int i = 0; i < 4; ++i) {
            float4 v = cur[i];
            float sx = v.x * scale, sy = v.y * scale, sz = v.z * scale, sw = v.w * scale;
            f16 hx = (f16)sx, hy = (f16)sy, hz = (f16)sz, hw = (f16)sw;
            f16 lx = (f16)(sx - (float)hx);
            f16 ly = (f16)(sy - (float)hy);
            f16 lz = (f16)(sz - (float)hz);
            f16 lw = (f16)(sw - (float)hw);
            int q   = sq + i;                                  // 0..15
            int off = swz_base(srow, q >> 1) + (q & 1) * 4;    // fp16 elems
            *(f16x4*)&dstH[off] = (f16x4){hx, hy, hz, hw};
            *(f16x4*)&dstL[off] = (f16x4){lx, ly, lz, lw};
        }
        __syncthreads();   // LDS planes visible

        // ---- compute: 2 K-subblocks of 32, 3-plane mfma, 2 expert frags ----
        const int arow  = wm * 16 + col;
        const int brow0 = wn * 32 + col;
        const int brow1 = brow0 + 16;
        #pragma unroll
        for (int s2 = 0; s2 < 2; ++s2) {
            int u = s2 * 4 + grp;
            f16x8 ah  = *(const f16x8*)&Ah[swz_base(arow,  u)];
            f16x8 al  = *(const f16x8*)&Al[swz_base(arow,  u)];
            f16x8 b0h = *(const f16x8*)&Bh[swz_base(brow0, u)];
            f16x8 b0l = *(const f16x8*)&Bl[swz_base(brow0, u)];
            f16x8 b1h = *(const f16x8*)&Bh[swz_base(brow1, u)];
            f16x8 b1l = *(const f16x8*)&Bl[swz_base(brow1, u)];
            acc0 = __builtin_amdgcn_mfma_f32_16x16x32_f16(ah, b0h, acc0, 0, 0, 0);
            acc0 = __builtin_amdgcn_mfma_f32_16x16x32_f16(ah, b0l, acc0, 0, 0, 0);
            acc0 = __builtin_amdgcn_mfma_f32_16x16x32_f16(al, b0h, acc0, 0, 0, 0);
            acc1 = __builtin_amdgcn_mfma_f32_16x16x32_f16(ah, b1h, acc1, 0, 0, 0);
            acc1 = __builtin_amdgcn_mfma_f32_16x16x32_f16(ah, b1l, acc1, 0, 0, 0);
            acc1 = __builtin_amdgcn_mfma_f32_16x16x32_f16(al, b1h, acc1, 0, 0, 0);
        }

        #pragma unroll
        for (int i = 0; i < 4; ++i) cur[i] = nxt[i];
    }

    // ---- epilogue: fused top-2 + softmax ----
    // C layout (verified gfx950): lane holds C[row=(lane>>4)*4+r][col=lane&15]
    // i.e. token (wm*16 + grp*4 + r), experts wn*32+col (acc0) / +16 (acc1).
    #pragma unroll
    for (int r = 0; r < 4; ++r) {
        float va = acc0[r], vb = acc1[r];
        int   ia = wn * 32 + col, ib = ia + 16;
        float v0, v1; int i0, i1;
        if (va >= vb) { v0 = va; i0 = ia; v1 = vb; i1 = ib; }
        else          { v0 = vb; i0 = ib; v1 = va; i1 = ia; }
        // butterfly top-2 over the 16-lane group (32 experts per wave)
        #pragma unroll
        for (int m = 1; m <= 8; m <<= 1) {
            float ov0 = __shfl_xor(v0, m, 64);
            int   oi0 = __shfl_xor(i0, m, 64);
            float ov1 = __shfl_xor(v1, m, 64);
            int   oi1 = __shfl_xor(i1, m, 64);
            bool ob = (ov0 > v0) || (ov0 == v0 && oi0 < i0);
            if (ob) {
                bool k2 = (v0 > ov1) || (v0 == ov1 && i0 < oi1);
                v1 = k2 ? v0 : ov1; i1 = k2 ? i0 : oi1;
                v0 = ov0; i0 = oi0;
            } else {
                bool k2 = (ov0 > v1) || (ov0 == v1 && oi0 < i1);
                v1 = k2 ? ov0 : v1; i1 = k2 ? oi0 : i1;
            }
        }
        if (col == 0) {
            int tl = wm * 16 + grp * 4 + r;
            red[wn][tl][0] = v0; red[wn][tl][1] = (float)i0;
            red[wn][tl][2] = v1; red[wn][tl][3] = (float)i1;
        }
    }
    __syncthreads();

    if (t < BM) {
        float a0 = red[0][t][0]; int ai0 = (int)red[0][t][1];
        float a1 = red[0][t][2]; int ai1 = (int)red[0][t][3];
        float b0 = red[1][t][0]; int bi0 = (int)red[1][t][1];
        float b1 = red[1][t][2]; int bi1 = (int)red[1][t][3];
        float v0, v1; int i0, i1;
        bool bb = (b0 > a0) || (b0 == a0 && bi0 < ai0);
        if (bb) {
            v0 = b0; i0 = bi0;
            bool k2 = (a0 > b1) || (a0 == b1 && ai0 < bi1);
            v1 = k2 ? a0 : b1; i1 = k2 ? ai0 : bi1;
        } else {
            v0 = a0; i0 = ai0;
            bool k2 = (b0 > a1) || (b0 == a1 && bi0 < ai1);
            v1 = k2 ? b0 : a1; i1 = k2 ? bi0 : ai1;
        }
        // softmax over [v0, v1] (descending, scaled logits: divide diff by 64)
        float d  = (v1 - v0) * (1.0f / 64.0f);
        float e  = expf(d);
        float g0 = 1.0f / (1.0f + e);
        float g1 = e / (1.0f + e);

        int tok = blk * BM + t;
        out[(size_t)tok * 2 + 0] = g0;
        out[(size_t)tok * 2 + 1] = g1;
        out[(size_t)NTOK * 2 + (size_t)tok * 2 + 0] = (float)i0;
        out[(size_t)NTOK * 2 + (size_t)tok * 2 + 1] = (float)i1;
    }
}

extern "C" void kernel_launch(void* const* d_in, const int* in_sizes, int n_in,
                              void* d_out, int out_size, void* d_ws, size_t ws_size,
                              hipStream_t stream) {
    const float* x = (const float*)d_in[0];   // [16384, 4096] f32
    const float* w = (const float*)d_in[1];   // [64, 4096] f32
    float* out = (float*)d_out;               // gates [16384,2] then idx-as-f32 [16384,2]
    (void)in_sizes; (void)n_in; (void)out_size; (void)d_ws; (void)ws_size;

    dim3 grid(NTOK / BM);   // 256 blocks, one 64-token tile each
    dim3 block(512);        // 8 waves: 4 token-quarters x 2 expert-halves
    topk_gate_kernel<<<grid, block, 0, stream>>>(x, w, out);
}